// Round 11
// baseline (111.757 us; speedup 1.0000x reference)
//
#include <hip/hip_runtime.h>
#include <math.h>

#define NB    2048
#define G2    32              // K2 blocks; each owns NB/G2 buckets
#define TBLK  512
#define OWNB  (NB / G2)       // 64 buckets per block
#define CAP   1280            // owned-element stash (mean 512, sd ~22 -> 34 sigma)
#define NSEG  (NB / 64)       // 32 scan segments

// ws layout (bytes):
//   0       partialF[rows][NB]  rows = ceil(n/TBLK) (= 32) ; 512 KB reserved
//   524288  wsum (f32)          zeroed by K1 block 0
//   524292  done (i32)          zeroed by K1 block 0
// Everything written before read each call -> poison-safe.
// No grid sync, no coop launch: K1->K2 kernel boundary is the only sync.

__device__ __forceinline__ int bucket_of(float d) {
    int b = (int)(d * (float)NB);          // monotone non-decreasing in d
    return min(max(b, 0), NB - 1);
}

// K1: per-chunk LDS histogram -> partial row. 1 element/thread, 512 LDS atomics/block.
__global__ __launch_bounds__(TBLK)
void k1_hist(const float* __restrict__ hazard,
             const float* __restrict__ durations,
             float* __restrict__ partialF,
             float* __restrict__ wsum, int* __restrict__ done, int n) {
    __shared__ float hist[NB];
    const int tid = threadIdx.x, blk = blockIdx.x;
    #pragma unroll
    for (int k = 0; k < NB / TBLK; ++k) hist[tid + k * TBLK] = 0.0f;
    __syncthreads();
    const int i = blk * TBLK + tid;
    if (i < n) atomicAdd(&hist[bucket_of(durations[i])], expf(hazard[i]));
    __syncthreads();
    #pragma unroll
    for (int k = 0; k < NB / TBLK; ++k) {
        int idx = tid + k * TBLK;
        partialF[blk * NB + idx] = hist[idx];       // coalesced
    }
    if (blk == 0 && tid == 0) { *wsum = 0.0f; *done = 0; }
}

// K2: per-block reduce partials + shuffle-scan -> suffix sums; stash owned
// elements; LDS bucket-sort; loss; ticketed finalize.
__global__ __launch_bounds__(TBLK)
void k2_loss(const float* __restrict__ hazard,
             const float* __restrict__ durations,
             const float* __restrict__ events,
             const float* __restrict__ partialF, int rows,
             float* __restrict__ wsum, int* __restrict__ done,
             float* __restrict__ out, int n) {
    __shared__ float scan[NB];                      // 8 KB  reversed inclusive scan
    __shared__ float segSum[NSEG], segOff[NSEG];
    __shared__ float sd[CAP], se[CAP], sh[CAP];     // 15 KB stash
    __shared__ int   sidx[CAP];                     // 5 KB
    __shared__ float bd[CAP], be[CAP];              // 10 KB bucket-sorted
    __shared__ int   lcnt[OWNB], loff[OWNB], lcur[OWNB];
    __shared__ int   nOwn;
    __shared__ float wpart[TBLK / 64];

    const int tid  = threadIdx.x, blk = blockIdx.x;
    const int base = blk * OWNB;
    const int lane = tid & 63, w = tid >> 6;

    if (tid < OWNB) lcnt[tid] = 0;
    if (tid == 0) nOwn = 0;
    __syncthreads();

    // ---- stash stream: find owned elements (no histogram work) ----
    for (int j = tid; j < n; j += TBLK) {           // coalesced d,h reads
        float d = durations[j];
        float h = hazard[j];
        int lb = bucket_of(d) - base;
        if (lb >= 0 && lb < OWNB) {                 // ~512 of 16384 per block
            int p = atomicAdd(&nOwn, 1);
            if (p < CAP) {
                sd[p] = d; sh[p] = h; se[p] = expf(h); sidx[p] = j;
                atomicAdd(&lcnt[lb], 1);
            }
        }
    }

    // ---- reduce partial rows at reversed index + wave-segment scan ----
    // scan index k corresponds to bucket NB-1-k; inclusive prefix of reversed
    // histogram == suffix sums.
    #pragma unroll
    for (int r = 0; r < 4; ++r) {
        int s = w * 4 + r;                          // wave w owns segments 4w..4w+3
        int k = s * 64 + lane;
        float v = 0.0f;
        for (int g = 0; g < rows; ++g)
            v += partialF[g * NB + (NB - 1 - k)];   // coalesced (descending)
        #pragma unroll
        for (int o = 1; o < 64; o <<= 1) {          // inclusive wave scan
            float y = __shfl_up(v, o, 64);
            if (lane >= o) v += y;
        }
        scan[k] = v;
        if (lane == 63) segSum[s] = v;
    }
    __syncthreads();
    if (tid < NSEG) {                               // 32 lanes of wave 0
        float v = segSum[tid];
        float x = v;
        #pragma unroll
        for (int o = 1; o < NSEG; o <<= 1) {
            float y = __shfl_up(x, o, 64);
            if (tid >= o) x += y;
        }
        segOff[tid] = x - v;                        // exclusive segment offset
    }
    __syncthreads();
    #pragma unroll
    for (int r = 0; r < 4; ++r) {
        int s = w * 4 + r;
        scan[s * 64 + lane] += segOff[s];
    }
    __syncthreads();
    // scan[k] = sum_{t<=k} hist[NB-1-t]; suffixGT[b] = scan[NB-2-b] (b<NB-1)

    // ---- exclusive scan of 64 owned-bucket counts (one wave) ----
    if (tid < 64) {
        int v = lcnt[tid];
        int x = v;
        #pragma unroll
        for (int o = 1; o < 64; o <<= 1) {
            int y = __shfl_up(x, o, 64);
            if (tid >= o) x += y;
        }
        loff[tid] = x - v;
        lcur[tid] = x - v;
    }
    __syncthreads();

    // ---- bucket-sorted LDS scatter of owned elements ----
    const int tot = min(nOwn, CAP);
    for (int p = tid; p < tot; p += TBLK) {
        int lb = bucket_of(sd[p]) - base;
        int q  = atomicAdd(&lcur[lb], 1);
        bd[q] = sd[p]; be[q] = se[p];
    }
    __syncthreads();

    // ---- loss for owned elements (all gathers hit LDS) ----
    float local = 0.0f;
    for (int p = tid; p < tot; p += TBLK) {
        float d  = sd[p];
        int   b  = bucket_of(d);
        int   lb = b - base;
        float s  = (b + 1 < NB) ? scan[NB - 2 - b] : 0.0f;
        int off = loff[lb], c = lcnt[lb];
        for (int t = 0; t < c; ++t) {               // avg 8, max ~35, LDS reads
            float dj = bd[off + t];
            s += (dj >= d) ? be[off + t] : 0.0f;    // includes j==i -> s > 0
        }
        local += (sh[p] - logf(s)) * events[sidx[p]];
    }

    // ---- block reduce -> ticketed finalize (proven R0 pattern) ----
    #pragma unroll
    for (int o = 32; o > 0; o >>= 1)
        local += __shfl_down(local, o, 64);
    if ((tid & 63) == 0) wpart[tid >> 6] = local;
    __syncthreads();
    if (tid == 0) {
        float t = 0.0f;
        #pragma unroll
        for (int ww = 0; ww < TBLK / 64; ++ww) t += wpart[ww];
        atomicAdd(wsum, t);
        __threadfence();
        int ticket = atomicAdd(done, 1);
        if (ticket == (int)gridDim.x - 1)
            out[0] = -atomicAdd(wsum, 0.0f) / (float)n;
    }
}

extern "C" void kernel_launch(void* const* d_in, const int* in_sizes, int n_in,
                              void* d_out, int out_size, void* d_ws, size_t ws_size,
                              hipStream_t stream) {
    const float* hazard    = (const float*)d_in[0];
    const float* durations = (const float*)d_in[1];
    const float* events    = (const float*)d_in[2];
    float* out = (float*)d_out;
    const int n = in_sizes[1];

    char*  ws       = (char*)d_ws;
    float* partialF = (float*)(ws + 0);
    float* wsum     = (float*)(ws + 524288);
    int*   done     = (int*)  (ws + 524292);

    const int rows = (n + TBLK - 1) / TBLK;         // 32 for n=16384

    k1_hist<<<rows, TBLK, 0, stream>>>(hazard, durations, partialF, wsum, done, n);
    k2_loss<<<G2, TBLK, 0, stream>>>(hazard, durations, events, partialF, rows,
                                     wsum, done, out, n);
}

// Round 13
// 83.692 us; speedup vs baseline: 1.3353x; 1.3353x over previous
//
#include <hip/hip_runtime.h>
#include <math.h>

#define NB    2048
#define G2    32              // K2 blocks; each owns NB/G2 buckets
#define TBLK  512
#define OWNB  (NB / G2)       // 64 buckets per block
#define CAP   1280            // owned-element stash (mean 512, sd ~22 -> 34 sigma)
#define NSEG  (NB / 64)       // 32 scan segments

// ws layout (bytes):
//   0       partialF[rows][NB]  rows = ceil(n/TBLK) (= 32); 512 KB reserved
//   524288  wsum (f32)          zeroed by K1 block 0
//   524292  done (i32)          zeroed by K1 block 0
// Everything written before read each call -> poison-safe.
// No grid sync, no coop launch: K1->K2 kernel boundary is the only sync.

__device__ __forceinline__ int bucket_of(float d) {
    int b = (int)(d * (float)NB);          // monotone non-decreasing in d
    return min(max(b, 0), NB - 1);
}

// K1: per-chunk LDS histogram -> partial row. 1 element/thread.
__global__ __launch_bounds__(TBLK)
void k1_hist(const float* __restrict__ hazard,
             const float* __restrict__ durations,
             float* __restrict__ partialF,
             float* __restrict__ wsum, int* __restrict__ done, int n) {
    __shared__ float hist[NB];
    const int tid = threadIdx.x, blk = blockIdx.x;
    #pragma unroll
    for (int k = 0; k < NB / TBLK; ++k) hist[tid + k * TBLK] = 0.0f;
    __syncthreads();
    const int i = blk * TBLK + tid;
    if (i < n) atomicAdd(&hist[bucket_of(durations[i])], expf(hazard[i]));
    __syncthreads();
    #pragma unroll
    for (int k = 0; k < NB / TBLK; ++k) {
        int idx = tid + k * TBLK;
        partialF[blk * NB + idx] = hist[idx];       // coalesced
    }
    if (blk == 0 && tid == 0) { *wsum = 0.0f; *done = 0; }
}

// K2: reduce partials (ILP-4) + shuffle-scan -> suffix sums; float4 stash
// stream; LDS bucket-sort; loss; ticketed finalize.
__global__ __launch_bounds__(TBLK)
void k2_loss(const float* __restrict__ hazard,
             const float* __restrict__ durations,
             const float* __restrict__ events,
             const float* __restrict__ partialF, int rows,
             float* __restrict__ wsum, int* __restrict__ done,
             float* __restrict__ out, int n) {
    __shared__ float scan[NB];                      // 8 KB reversed inclusive scan
    __shared__ float segSum[NSEG], segOff[NSEG];
    __shared__ float sd[CAP], se[CAP], sh[CAP];     // 15 KB stash
    __shared__ int   sidx[CAP];                     // 5 KB
    __shared__ float bd[CAP], be[CAP];              // 10 KB bucket-sorted
    __shared__ int   lcnt[OWNB], loff[OWNB], lcur[OWNB];
    __shared__ int   nOwn;
    __shared__ float wpart[TBLK / 64];

    const int tid  = threadIdx.x, blk = blockIdx.x;
    const int base = blk * OWNB;
    const int lane = tid & 63, w = tid >> 6;

    if (tid < OWNB) lcnt[tid] = 0;
    if (tid == 0) nOwn = 0;
    __syncthreads();

    // ---- stash stream: float4 loads, 8 iterations (was 32 scalar) ----
    #define STASH(dd, hh, jj) {                                          \
        int lb_ = bucket_of(dd) - base;                                  \
        if (lb_ >= 0 && lb_ < OWNB) {                                    \
            int p_ = atomicAdd(&nOwn, 1);                                \
            if (p_ < CAP) {                                              \
                sd[p_] = (dd); sh[p_] = (hh); se[p_] = expf(hh);         \
                sidx[p_] = (jj); atomicAdd(&lcnt[lb_], 1);               \
            } } }
    const int n4 = n >> 2;
    const float4* dv4 = (const float4*)durations;
    const float4* hv4 = (const float4*)hazard;
    for (int q = tid; q < n4; q += TBLK) {          // coalesced 16B/lane
        float4 dv = dv4[q];
        float4 hv = hv4[q];
        int j0 = q << 2;
        STASH(dv.x, hv.x, j0);
        STASH(dv.y, hv.y, j0 + 1);
        STASH(dv.z, hv.z, j0 + 2);
        STASH(dv.w, hv.w, j0 + 3);
    }
    for (int j = (n4 << 2) + tid; j < n; j += TBLK) // tail (n % 4)
        STASH(durations[j], hazard[j], j);
    #undef STASH

    // ---- reduce partial rows (4 accumulators) + wave-segment scan ----
    #pragma unroll
    for (int r = 0; r < 4; ++r) {
        int s = w * 4 + r;                          // wave w owns segments 4w..4w+3
        int k = s * 64 + lane;
        int ridx = NB - 1 - k;                      // reversed -> suffix via prefix
        float v0 = 0.0f, v1 = 0.0f, v2 = 0.0f, v3 = 0.0f;
        int g = 0;
        for (; g + 3 < rows; g += 4) {              // 4 loads in flight
            v0 += partialF[(g + 0) * NB + ridx];
            v1 += partialF[(g + 1) * NB + ridx];
            v2 += partialF[(g + 2) * NB + ridx];
            v3 += partialF[(g + 3) * NB + ridx];
        }
        for (; g < rows; ++g) v0 += partialF[g * NB + ridx];
        float v = (v0 + v1) + (v2 + v3);
        #pragma unroll
        for (int o = 1; o < 64; o <<= 1) {          // inclusive wave scan
            float y = __shfl_up(v, o, 64);
            if (lane >= o) v += y;
        }
        scan[k] = v;
        if (lane == 63) segSum[s] = v;
    }
    __syncthreads();
    if (tid < NSEG) {                               // 32 lanes of wave 0
        float v = segSum[tid];
        float x = v;
        #pragma unroll
        for (int o = 1; o < NSEG; o <<= 1) {
            float y = __shfl_up(x, o, 64);
            if (tid >= o) x += y;
        }
        segOff[tid] = x - v;                        // exclusive segment offset
    }
    __syncthreads();
    #pragma unroll
    for (int r = 0; r < 4; ++r) {
        int s = w * 4 + r;
        scan[s * 64 + lane] += segOff[s];
    }
    __syncthreads();
    // scan[k] = sum_{t<=k} hist[NB-1-t]; suffixGT[b] = scan[NB-2-b] (b<NB-1)

    // ---- exclusive scan of 64 owned-bucket counts (one wave) ----
    if (tid < 64) {
        int v = lcnt[tid];
        int x = v;
        #pragma unroll
        for (int o = 1; o < 64; o <<= 1) {
            int y = __shfl_up(x, o, 64);
            if (tid >= o) x += y;
        }
        loff[tid] = x - v;
        lcur[tid] = x - v;
    }
    __syncthreads();

    // ---- bucket-sorted LDS scatter of owned elements ----
    const int tot = min(nOwn, CAP);
    for (int p = tid; p < tot; p += TBLK) {
        int lb = bucket_of(sd[p]) - base;
        int q  = atomicAdd(&lcur[lb], 1);
        bd[q] = sd[p]; be[q] = se[p];
    }
    __syncthreads();

    // ---- loss for owned elements (all gathers hit LDS) ----
    float local = 0.0f;
    for (int p = tid; p < tot; p += TBLK) {
        float d  = sd[p];
        int   b  = bucket_of(d);
        int   lb = b - base;
        float s  = (b + 1 < NB) ? scan[NB - 2 - b] : 0.0f;
        int off = loff[lb], c = lcnt[lb];
        for (int t = 0; t < c; ++t) {               // avg 8, max ~35, LDS reads
            float dj = bd[off + t];
            s += (dj >= d) ? be[off + t] : 0.0f;    // includes j==i -> s > 0
        }
        local += (sh[p] - logf(s)) * events[sidx[p]];
    }

    // ---- block reduce -> ticketed finalize (proven pattern) ----
    #pragma unroll
    for (int o = 32; o > 0; o >>= 1)
        local += __shfl_down(local, o, 64);
    if ((tid & 63) == 0) wpart[tid >> 6] = local;
    __syncthreads();
    if (tid == 0) {
        float t = 0.0f;
        #pragma unroll
        for (int ww = 0; ww < TBLK / 64; ++ww) t += wpart[ww];
        atomicAdd(wsum, t);
        __threadfence();
        int ticket = atomicAdd(done, 1);
        if (ticket == (int)gridDim.x - 1)
            out[0] = -atomicAdd(wsum, 0.0f) / (float)n;
    }
}

extern "C" void kernel_launch(void* const* d_in, const int* in_sizes, int n_in,
                              void* d_out, int out_size, void* d_ws, size_t ws_size,
                              hipStream_t stream) {
    const float* hazard    = (const float*)d_in[0];
    const float* durations = (const float*)d_in[1];
    const float* events    = (const float*)d_in[2];
    float* out = (float*)d_out;
    const int n = in_sizes[1];

    char*  ws       = (char*)d_ws;
    float* partialF = (float*)(ws + 0);
    float* wsum     = (float*)(ws + 524288);
    int*   done     = (int*)  (ws + 524292);

    const int rows = (n + TBLK - 1) / TBLK;         // 32 for n=16384

    k1_hist<<<rows, TBLK, 0, stream>>>(hazard, durations, partialF, wsum, done, n);
    k2_loss<<<G2, TBLK, 0, stream>>>(hazard, durations, events, partialF, rows,
                                     wsum, done, out, n);
}

// Round 15
// 75.581 us; speedup vs baseline: 1.4786x; 1.1073x over previous
//
#include <hip/hip_runtime.h>
#include <math.h>

#define NB    2048
#define G2    32              // K2 blocks; each owns NB/G2 buckets
#define TBLK  512
#define R1T   1024            // K1 threads; K1 handles 2 elems/thread
#define OWNB  (NB / G2)       // 64 buckets per block
#define CAP   1280            // owned-element stash (mean 512, sd ~22 -> 34 sigma)
#define NSEG  (NB / 64)       // 32 scan segments

// ws layout (bytes):
//   0       partialF[rows][NB]  rows = ceil(n/2048) (= 8); 512 KB reserved
//   524288  wsum (f32)          zeroed by K1 block 0
//   524292  done (i32)          zeroed by K1 block 0
// Everything written before read each call -> poison-safe.
// No grid sync, no coop launch: K1->K2 kernel boundary is the only sync.

__device__ __forceinline__ int bucket_of(float d) {
    int b = (int)(d * (float)NB);          // monotone non-decreasing in d
    return min(max(b, 0), NB - 1);
}

// K1: per-chunk LDS histogram (2048 elems/block via float2) -> partial row.
__global__ __launch_bounds__(R1T)
void k1_hist(const float* __restrict__ hazard,
             const float* __restrict__ durations,
             float* __restrict__ partialF,
             float* __restrict__ wsum, int* __restrict__ done, int n) {
    __shared__ float hist[NB];
    const int tid = threadIdx.x, blk = blockIdx.x;
    #pragma unroll
    for (int k = 0; k < NB / R1T; ++k) hist[tid + k * R1T] = 0.0f;
    __syncthreads();
    const int i2 = blk * (R1T * 2) + tid * 2;      // even -> 8B aligned
    if (i2 + 1 < n) {
        float2 dv = *(const float2*)(durations + i2);
        float2 hv = *(const float2*)(hazard + i2);
        atomicAdd(&hist[bucket_of(dv.x)], expf(hv.x));
        atomicAdd(&hist[bucket_of(dv.y)], expf(hv.y));
    } else if (i2 < n) {
        atomicAdd(&hist[bucket_of(durations[i2])], expf(hazard[i2]));
    }
    __syncthreads();
    #pragma unroll
    for (int k = 0; k < NB / R1T; ++k) {
        int idx = tid + k * R1T;
        partialF[blk * NB + idx] = hist[idx];      // coalesced
    }
    if (blk == 0 && tid == 0) { *wsum = 0.0f; *done = 0; }
}

// K2: duration-only stash stream; lazy hazard/events gather for owned;
// ILP-4 reduce of 8 partial rows + shuffle-scan; LDS bucket-sort; loss; ticket.
__global__ __launch_bounds__(TBLK)
void k2_loss(const float* __restrict__ hazard,
             const float* __restrict__ durations,
             const float* __restrict__ events,
             const float* __restrict__ partialF, int rows,
             float* __restrict__ wsum, int* __restrict__ done,
             float* __restrict__ out, int n) {
    __shared__ float scan[NB];                      // 8 KB reversed inclusive scan
    __shared__ float segSum[NSEG], segOff[NSEG];
    __shared__ float sd[CAP], se[CAP], sh[CAP], sev[CAP];  // 20 KB stash
    __shared__ int   sidx[CAP];                     // 5 KB
    __shared__ float bd[CAP], be[CAP];              // 10 KB bucket-sorted
    __shared__ int   lcnt[OWNB], loff[OWNB], lcur[OWNB];
    __shared__ int   nOwn;
    __shared__ float wpart[TBLK / 64];

    const int tid  = threadIdx.x, blk = blockIdx.x;
    const int base = blk * OWNB;
    const int lane = tid & 63, w = tid >> 6;

    if (tid < OWNB) lcnt[tid] = 0;
    if (tid == 0) nOwn = 0;
    __syncthreads();

    // ---- stash stream: DURATIONS ONLY, float4 (8 iterations) ----
    #define STASH(dd, jj) {                                              \
        int lb_ = bucket_of(dd) - base;                                  \
        if (lb_ >= 0 && lb_ < OWNB) {                                    \
            int p_ = atomicAdd(&nOwn, 1);                                \
            if (p_ < CAP) {                                              \
                sd[p_] = (dd); sidx[p_] = (jj);                          \
                atomicAdd(&lcnt[lb_], 1);                                \
            } } }
    const int n4 = n >> 2;
    const float4* dv4 = (const float4*)durations;
    for (int q = tid; q < n4; q += TBLK) {          // coalesced 16B/lane
        float4 dv = dv4[q];
        int j0 = q << 2;
        STASH(dv.x, j0);
        STASH(dv.y, j0 + 1);
        STASH(dv.z, j0 + 2);
        STASH(dv.w, j0 + 3);
    }
    for (int j = (n4 << 2) + tid; j < n; j += TBLK) // tail (n % 4)
        STASH(durations[j], j);
    #undef STASH
    __syncthreads();                                // finalize nOwn/stash

    // ---- lazy gather: hazard/events only for owned (~1 load pair/thread) ----
    const int tot = min(nOwn, CAP);
    for (int p = tid; p < tot; p += TBLK) {
        int j = sidx[p];
        float h = hazard[j];
        sh[p] = h; se[p] = expf(h); sev[p] = events[j];
    }

    // ---- reduce partial rows (4 accumulators, rows=8 -> 2 steps) + scan ----
    #pragma unroll
    for (int r = 0; r < 4; ++r) {
        int s = w * 4 + r;                          // wave w owns segments 4w..4w+3
        int k = s * 64 + lane;
        int ridx = NB - 1 - k;                      // reversed -> suffix via prefix
        float v0 = 0.0f, v1 = 0.0f, v2 = 0.0f, v3 = 0.0f;
        int g = 0;
        for (; g + 3 < rows; g += 4) {              // 4 loads in flight
            v0 += partialF[(g + 0) * NB + ridx];
            v1 += partialF[(g + 1) * NB + ridx];
            v2 += partialF[(g + 2) * NB + ridx];
            v3 += partialF[(g + 3) * NB + ridx];
        }
        for (; g < rows; ++g) v0 += partialF[g * NB + ridx];
        float v = (v0 + v1) + (v2 + v3);
        #pragma unroll
        for (int o = 1; o < 64; o <<= 1) {          // inclusive wave scan
            float y = __shfl_up(v, o, 64);
            if (lane >= o) v += y;
        }
        scan[k] = v;
        if (lane == 63) segSum[s] = v;
    }
    __syncthreads();
    if (tid < NSEG) {                               // 32 lanes of wave 0
        float v = segSum[tid];
        float x = v;
        #pragma unroll
        for (int o = 1; o < NSEG; o <<= 1) {
            float y = __shfl_up(x, o, 64);
            if (tid >= o) x += y;
        }
        segOff[tid] = x - v;                        // exclusive segment offset
    }
    __syncthreads();
    #pragma unroll
    for (int r = 0; r < 4; ++r) {
        int s = w * 4 + r;
        scan[s * 64 + lane] += segOff[s];
    }
    __syncthreads();
    // scan[k] = sum_{t<=k} hist[NB-1-t]; suffixGT[b] = scan[NB-2-b] (b<NB-1)

    // ---- exclusive scan of 64 owned-bucket counts (one wave) ----
    if (tid < 64) {
        int v = lcnt[tid];
        int x = v;
        #pragma unroll
        for (int o = 1; o < 64; o <<= 1) {
            int y = __shfl_up(x, o, 64);
            if (tid >= o) x += y;
        }
        loff[tid] = x - v;
        lcur[tid] = x - v;
    }
    __syncthreads();

    // ---- bucket-sorted LDS scatter of owned elements ----
    for (int p = tid; p < tot; p += TBLK) {
        int lb = bucket_of(sd[p]) - base;
        int q  = atomicAdd(&lcur[lb], 1);
        bd[q] = sd[p]; be[q] = se[p];
    }
    __syncthreads();

    // ---- loss for owned elements (all gathers hit LDS) ----
    float local = 0.0f;
    for (int p = tid; p < tot; p += TBLK) {
        float d  = sd[p];
        int   b  = bucket_of(d);
        int   lb = b - base;
        float s  = (b + 1 < NB) ? scan[NB - 2 - b] : 0.0f;
        int off = loff[lb], c = lcnt[lb];
        for (int t = 0; t < c; ++t) {               // avg 8, max ~35, LDS reads
            float dj = bd[off + t];
            s += (dj >= d) ? be[off + t] : 0.0f;    // includes j==i -> s > 0
        }
        local += (sh[p] - logf(s)) * sev[p];
    }

    // ---- block reduce -> ticketed finalize (proven pattern) ----
    #pragma unroll
    for (int o = 32; o > 0; o >>= 1)
        local += __shfl_down(local, o, 64);
    if ((tid & 63) == 0) wpart[tid >> 6] = local;
    __syncthreads();
    if (tid == 0) {
        float t = 0.0f;
        #pragma unroll
        for (int ww = 0; ww < TBLK / 64; ++ww) t += wpart[ww];
        atomicAdd(wsum, t);
        __threadfence();
        int ticket = atomicAdd(done, 1);
        if (ticket == (int)gridDim.x - 1)
            out[0] = -atomicAdd(wsum, 0.0f) / (float)n;
    }
}

extern "C" void kernel_launch(void* const* d_in, const int* in_sizes, int n_in,
                              void* d_out, int out_size, void* d_ws, size_t ws_size,
                              hipStream_t stream) {
    const float* hazard    = (const float*)d_in[0];
    const float* durations = (const float*)d_in[1];
    const float* events    = (const float*)d_in[2];
    float* out = (float*)d_out;
    const int n = in_sizes[1];

    char*  ws       = (char*)d_ws;
    float* partialF = (float*)(ws + 0);
    float* wsum     = (float*)(ws + 524288);
    int*   done     = (int*)  (ws + 524292);

    const int rows = (n + (R1T * 2) - 1) / (R1T * 2);   // 8 for n=16384

    k1_hist<<<rows, R1T, 0, stream>>>(hazard, durations, partialF, wsum, done, n);
    k2_loss<<<G2, TBLK, 0, stream>>>(hazard, durations, events, partialF, rows,
                                     wsum, done, out, n);
}